// Round 2
// baseline (289.234 us; speedup 1.0000x reference)
//
#include <hip/hip_runtime.h>
#include <math.h>

#define B_ 32
#define N_ 64
#define K_ 128
#define NPAIR (B_*N_*N_)
#define PREP_TOTAL 733184

typedef __attribute__((ext_vector_type(8))) short short8;
typedef __attribute__((ext_vector_type(8))) __bf16 bf16x8;
typedef __attribute__((ext_vector_type(4))) float floatx4;

__device__ __forceinline__ float silu_f(float x) {
    return x / (1.0f + expf(-x));
}

__device__ __forceinline__ short f2bf(float x) {
    union { float f; unsigned u; } v; v.f = x;
    unsigned r = (v.u + 0x7FFFu + ((v.u >> 16) & 1u)) >> 16;
    return (short)r;
}
__device__ __forceinline__ float bf2f(short s) {
    union { unsigned u; float f; } v;
    v.u = ((unsigned)(unsigned short)s) << 16;
    return v.f;
}
__device__ __forceinline__ bf16x8 ld_frag(const short* p) {
    short8 r = *(const short8*)p;
    return __builtin_bit_cast(bf16x8, r);
}

// ---------------------------------------------------------------------------
// Kernel 0: weight prep -> bf16 transposed layouts (B-operand: BT[n][k])
// short offsets:
//   0       r1w1T [64][64]
//   4096    r1w2T [64][64]
//   8192    r2w1T [64][64]
//   12288   r2w2T [64][64]
//   16384   r2w3T [256][64]
//   32768   wT0   [512][704] (zero-pad k>=641)
//   393216  wT1   [512][512]
//   655360  w0T_1 [64][32]  (r1w0^T zero-pad k>=8)
//   657408  w0T_2 [64][32]  (r2w0^T zero-pad k>=8)
//   659456  w3T_1 [384][64] (r1w3^T)
//   684032  lcatT [384][128] ([l0|l1|l2]^T concat along n)
//   733184  end
// ---------------------------------------------------------------------------
__global__ __launch_bounds__(256) void prep_kernel(
    const float* __restrict__ r1w1, const float* __restrict__ r1w2,
    const float* __restrict__ r2w1, const float* __restrict__ r2w2,
    const float* __restrict__ r2w3, const float* __restrict__ mw0,
    const float* __restrict__ mw1,
    const float* __restrict__ r1w0, const float* __restrict__ r2w0,
    const float* __restrict__ r1w3,
    const float* __restrict__ l0, const float* __restrict__ l1,
    const float* __restrict__ l2,
    short* __restrict__ dst)
{
    int idx = blockIdx.x * 256 + threadIdx.x;
    if (idx >= PREP_TOTAL) return;
    short v;
    if (idx < 4096) {
        int h = idx >> 6, k = idx & 63; v = f2bf(r1w1[k*64 + h]);
    } else if (idx < 8192) {
        int i = idx - 4096; int h = i >> 6, k = i & 63; v = f2bf(r1w2[k*64 + h]);
    } else if (idx < 12288) {
        int i = idx - 8192; int h = i >> 6, k = i & 63; v = f2bf(r2w1[k*64 + h]);
    } else if (idx < 16384) {
        int i = idx - 12288; int h = i >> 6, k = i & 63; v = f2bf(r2w2[k*64 + h]);
    } else if (idx < 32768) {
        int i = idx - 16384; int col = i >> 6, h = i & 63; v = f2bf(r2w3[h*256 + col]);
    } else if (idx < 393216) {
        int i = idx - 32768; int n = i / 704, k = i - n*704;
        v = (k < 641) ? f2bf(mw0[(size_t)k*512 + n]) : (short)0;
    } else if (idx < 655360) {
        int i = idx - 393216; int n = i >> 9, k = i & 511;
        v = f2bf(mw1[(size_t)k*512 + n]);
    } else if (idx < 657408) {
        int i = idx - 655360; int h = i >> 5, k = i & 31;
        v = (k < 8) ? f2bf(r1w0[k*64 + h]) : (short)0;
    } else if (idx < 659456) {
        int i = idx - 657408; int h = i >> 5, k = i & 31;
        v = (k < 8) ? f2bf(r2w0[k*64 + h]) : (short)0;
    } else if (idx < 684032) {
        int i = idx - 659456; int col = i >> 6, h = i & 63;
        v = f2bf(r1w3[(size_t)h*384 + col]);
    } else {
        int i = idx - 684032; int n = i >> 7, k = i & 127;
        float src = (n < 128) ? l0[(size_t)k*128 + n]
                  : (n < 256) ? l1[(size_t)k*128 + (n-128)]
                              : l2[(size_t)k*128 + (n-256)];
        v = f2bf(src);
    }
    dst[idx] = v;
}

// ---------------------------------------------------------------------------
// Kernel 1: per-pair geometry -> rad[8], Y1[3], Y2[5], maskf  (fp32)
// ---------------------------------------------------------------------------
__global__ __launch_bounds__(256) void geom_kernel(
    const float* __restrict__ pos, const float* __restrict__ cell,
    float* __restrict__ rad, float* __restrict__ Y1, float* __restrict__ Y2,
    float* __restrict__ maskf)
{
    int p = blockIdx.x * 256 + threadIdx.x;
    if (p >= NPAIR) return;
    int b = p >> 12;
    int ij = p & 4095;
    int i = ij >> 6, j = ij & 63;
    const float* pi = pos + (size_t)(b*N_ + i)*3;
    const float* pj = pos + (size_t)(b*N_ + j)*3;
    float d0 = pi[0]-pj[0], d1 = pi[1]-pj[1], d2 = pi[2]-pj[2];
    d0 -= rintf(d0); d1 -= rintf(d1); d2 -= rintf(d2);
    const float* C = cell + b*9;
    float dc0 = d0*C[0] + d1*C[3] + d2*C[6];
    float dc1 = d0*C[1] + d1*C[4] + d2*C[7];
    float dc2 = d0*C[2] + d1*C[5] + d2*C[8];
    float r2 = fmaxf(dc0*dc0 + dc1*dc1 + dc2*dc2, 1e-12f);
    float r = sqrtf(r2);
    bool m = (r < 5.0f) && (i != j);
    float mf = m ? 1.0f : 0.0f;
    float rs = m ? r : 1.0f;
    float inv_rs = 1.0f / rs;
    float x = dc0*inv_rs*mf, y = dc1*inv_rs*mf, z = dc2*inv_rs*mf;
    float u = r * 0.2f;
    float u2 = u*u, u4 = u2*u2, u5 = u4*u;
    float fc = 1.0f - 21.0f*u5 + 35.0f*u5*u - 15.0f*u5*u2;
    fc = (u < 1.0f) ? fc : 0.0f;
    float pref = 0.6324555320336759f * inv_rs * (fc * mf);
    float w = 0.6283185307179586f * rs;
    #pragma unroll
    for (int n = 1; n <= 8; n++)
        rad[(size_t)p*8 + (n-1)] = pref * sinf((float)n * w);
    const float s3  = 1.7320508075688772f;
    const float s5  = 2.23606797749979f;
    const float s15 = 3.872983346207417f;
    float* y1 = Y1 + (size_t)p*3;
    y1[0] = s3*x; y1[1] = s3*y; y1[2] = s3*z;
    float* y2 = Y2 + (size_t)p*5;
    y2[0] = s15*x*y;
    y2[1] = s15*y*z;
    y2[2] = 0.5f*s5*(3.0f*z*z - 1.0f);
    y2[3] = s15*x*z;
    y2[4] = 0.5f*s15*(x*x - y*y);
    maskf[p] = mf;
}

// ---------------------------------------------------------------------------
// Shared MFMA MLP layer: act[64][72]bf16 (LDS) @ WT[64n][64k]bf16 (global)
// -> silu -> dst[64][72]bf16 (normal layout). Wave wv owns rows [16wv,16wv+16).
// ---------------------------------------------------------------------------
__device__ __forceinline__ void mfma_layer(
    const short* __restrict__ src, const short* __restrict__ WT,
    const float* __restrict__ bias, short* __restrict__ dst,
    int wv, int qd, int nn)
{
    floatx4 acc[4];
    #pragma unroll
    for (int tt = 0; tt < 4; tt++) acc[tt] = (floatx4){0.f, 0.f, 0.f, 0.f};
    #pragma unroll
    for (int ks = 0; ks < 64; ks += 32) {
        bf16x8 a = ld_frag(&src[(wv*16 + nn)*72 + ks + qd*8]);
        #pragma unroll
        for (int tt = 0; tt < 4; tt++) {
            bf16x8 b = ld_frag(&WT[(tt*16 + nn)*64 + ks + qd*8]);
            acc[tt] = __builtin_amdgcn_mfma_f32_16x16x32_bf16(a, b, acc[tt], 0, 0, 0);
        }
    }
    #pragma unroll
    for (int tt = 0; tt < 4; tt++) {
        int col = tt*16 + nn;
        float bv = bias[col];
        #pragma unroll
        for (int i = 0; i < 4; i++) {
            int row = wv*16 + qd*4 + i;
            dst[row*72 + col] = f2bf(silu_f(acc[tt][i] + bv));
        }
    }
}

// Same but writes dst TRANSPOSED: dstT[col][row] (ld 72)
__device__ __forceinline__ void mfma_layer_T(
    const short* __restrict__ src, const short* __restrict__ WT,
    const float* __restrict__ bias, short* __restrict__ dstT,
    int wv, int qd, int nn)
{
    floatx4 acc[4];
    #pragma unroll
    for (int tt = 0; tt < 4; tt++) acc[tt] = (floatx4){0.f, 0.f, 0.f, 0.f};
    #pragma unroll
    for (int ks = 0; ks < 64; ks += 32) {
        bf16x8 a = ld_frag(&src[(wv*16 + nn)*72 + ks + qd*8]);
        #pragma unroll
        for (int tt = 0; tt < 4; tt++) {
            bf16x8 b = ld_frag(&WT[(tt*16 + nn)*64 + ks + qd*8]);
            acc[tt] = __builtin_amdgcn_mfma_f32_16x16x32_bf16(a, b, acc[tt], 0, 0, 0);
        }
    }
    #pragma unroll
    for (int tt = 0; tt < 4; tt++) {
        int col = tt*16 + nn;
        float bv = bias[col];
        #pragma unroll
        for (int i = 0; i < 4; i++) {
            int row = wv*16 + qd*4 + i;
            dstT[col*72 + row] = f2bf(silu_f(acc[tt][i] + bv));
        }
    }
}

// L0: rad_bf[64][40] (K zero-padded to 32) @ w0T[64][32] -> silu -> act[64][72]
__device__ __forceinline__ void mfma_layer0(
    const short* __restrict__ rad_bf, const short* __restrict__ w0T,
    const float* __restrict__ b0, short* __restrict__ dst,
    int wv, int qd, int nn)
{
    floatx4 acc[4];
    #pragma unroll
    for (int tt = 0; tt < 4; tt++) acc[tt] = (floatx4){0.f, 0.f, 0.f, 0.f};
    bf16x8 a = ld_frag(&rad_bf[(wv*16 + nn)*40 + qd*8]);
    #pragma unroll
    for (int tt = 0; tt < 4; tt++) {
        bf16x8 b = ld_frag(&w0T[(tt*16 + nn)*32 + qd*8]);
        acc[tt] = __builtin_amdgcn_mfma_f32_16x16x32_bf16(a, b, acc[tt], 0, 0, 0);
    }
    #pragma unroll
    for (int tt = 0; tt < 4; tt++) {
        int col = tt*16 + nn;
        float bv = b0[col];
        #pragma unroll
        for (int i = 0; i < 4; i++) {
            int row = wv*16 + qd*4 + i;
            dst[row*72 + col] = f2bf(silu_f(acc[tt][i] + bv));
        }
    }
}

// ---------------------------------------------------------------------------
// Kernel 2 (pass 1): one block per node. All GEMVs via MFMA.
// ---------------------------------------------------------------------------
__global__ __launch_bounds__(256) void pass1_kernel(
    const float* __restrict__ rad, const float* __restrict__ Y1g,
    const float* __restrict__ Y2g, const float* __restrict__ maskg,
    const float* __restrict__ wemb,
    const short* __restrict__ w0T, const float* __restrict__ b0,
    const short* __restrict__ w1T, const float* __restrict__ b1,
    const short* __restrict__ w2T, const float* __restrict__ b2,
    const short* __restrict__ w3T, const float* __restrict__ b3,
    const short* __restrict__ lcatT, const float* __restrict__ timeg,
    float* __restrict__ h1g, float* __restrict__ v1g, short* __restrict__ featsb)
{
    __shared__ __align__(16) short lds_a[2560];   // rad_bf [64][40]; later A2 [16][136]
    __shared__ __align__(16) short actA[64*72];
    __shared__ __align__(16) short actB[64*72];
    __shared__ __align__(16) short Ym_bf[16*72];  // A-operand of G (rows 9..15 zero)
    __shared__ __align__(16) short G_bf[16*72];   // A-operand of msg
    __shared__ __align__(16) float msg[1152];     // later P-extraction bufs (640 f)
    __shared__ float SY[9];
    __shared__ float q_s[128];
    int t = threadIdx.x;
    int wv = t >> 6, lane = t & 63, qd = lane >> 4, nn = lane & 15;
    int node = blockIdx.x;
    int b = node >> 6;
    size_t pbase = (size_t)node * 64;

    // stage rad -> bf16 [64][40], K zero-padded to 32
    for (int idx = t; idx < 2048; idx += 256) {
        int j = idx >> 5, k = idx & 31;
        lds_a[j*40 + k] = (k < 8) ? f2bf(rad[pbase*8 + j*8 + k]) : (short)0;
    }
    // Ym (bf16, masked) + SY via wave-0 shuffle reduction
    if (t < 64) {
        int j = t;
        float mf = maskg[pbase + j];
        float vals[9];
        vals[0] = mf;
        #pragma unroll
        for (int m = 0; m < 3; m++) vals[1+m] = Y1g[(pbase+j)*3 + m] * mf;
        #pragma unroll
        for (int m = 0; m < 5; m++) vals[4+m] = Y2g[(pbase+j)*5 + m] * mf;
        #pragma unroll
        for (int m = 0; m < 9; m++) Ym_bf[m*72 + j] = f2bf(vals[m]);
        #pragma unroll
        for (int m = 9; m < 16; m++) Ym_bf[m*72 + j] = 0;
        #pragma unroll
        for (int m = 0; m < 9; m++) {
            float s = vals[m];
            #pragma unroll
            for (int off = 32; off > 0; off >>= 1) s += __shfl_xor(s, off);
            if (j == 0) SY[m] = s;
        }
    }
    __syncthreads();

    mfma_layer0(lds_a, w0T, b0, actA, wv, qd, nn);
    __syncthreads();
    mfma_layer(actA, w1T, b1, actB, wv, qd, nn);
    __syncthreads();
    mfma_layer_T(actB, w2T, b2, actA, wv, qd, nn);   // hcT[h][j] -> actA
    __syncthreads();

    // G[m][h] = sum_j Ym[m][j]*hc[j][h]; wave wv owns h-tile [16wv,16wv+16)
    {
        floatx4 acc = (floatx4){0.f, 0.f, 0.f, 0.f};
        #pragma unroll
        for (int ks = 0; ks < 64; ks += 32) {
            bf16x8 a = ld_frag(&Ym_bf[nn*72 + ks + qd*8]);
            bf16x8 bb = ld_frag(&actA[(wv*16 + nn)*72 + ks + qd*8]);
            acc = __builtin_amdgcn_mfma_f32_16x16x32_bf16(a, bb, acc, 0, 0, 0);
        }
        #pragma unroll
        for (int i = 0; i < 4; i++)
            G_bf[(qd*4 + i)*72 + wv*16 + nn] = f2bf(acc[i]);
    }
    __syncthreads();

    // msg[m][k]: T[m][col] = G @ w3T (24 n-tiles, 6 per wave), then scale
    {
        floatx4 acc[6];
        #pragma unroll
        for (int tt = 0; tt < 6; tt++) acc[tt] = (floatx4){0.f, 0.f, 0.f, 0.f};
        #pragma unroll
        for (int ks = 0; ks < 64; ks += 32) {
            bf16x8 a = ld_frag(&G_bf[nn*72 + ks + qd*8]);
            #pragma unroll
            for (int tt = 0; tt < 6; tt++) {
                bf16x8 bb = ld_frag(&w3T[((wv*6 + tt)*16 + nn)*64 + ks + qd*8]);
                acc[tt] = __builtin_amdgcn_mfma_f32_16x16x32_bf16(a, bb, acc[tt], 0, 0, 0);
            }
        }
        #pragma unroll
        for (int tt = 0; tt < 6; tt++) {
            int col = (wv*6 + tt)*16 + nn;
            #pragma unroll
            for (int i = 0; i < 4; i++) {
                int m = qd*4 + i;
                if (m < 9) {
                    int c = (m == 0) ? 0 : ((m < 4) ? 1 : 2);
                    int k = col - c*128;
                    if (k >= 0 && k < 128)
                        msg[m*128 + k] = (acc[tt][i] + SY[m]*b3[col]) * wemb[k] * 0.0625f;
                }
            }
        }
    }
    __syncthreads();

    if (t < 128) {
        int k = t;
        float acc = 0.f;
        #pragma unroll
        for (int m = 4; m < 9; m++) { float v = msg[m*128 + k]; acc += v*v; }
        q_s[k] = acc;
    }
    __syncthreads();

    // A2 rows: 0=msg0, 1=q, 2..4=msg1..3, 5..15=0 -> lds_a as [16][136] bf16
    for (int idx = t; idx < 2048; idx += 256) {
        int r = idx >> 7, k = idx & 127;
        float v = (r == 0) ? msg[k]
                : (r == 1) ? q_s[k]
                : (r < 5)  ? msg[(r-1)*128 + k] : 0.f;
        lds_a[r*136 + k] = f2bf(v);
    }
    __syncthreads();

    // P = A2 @ lcatT (N=384, K=128). Extract: s1 = P[0][0:128] + P[1][256:384],
    // v1[m] = P[2+m][128:256].
    {
        floatx4 acc[6];
        #pragma unroll
        for (int tt = 0; tt < 6; tt++) acc[tt] = (floatx4){0.f, 0.f, 0.f, 0.f};
        #pragma unroll
        for (int ks = 0; ks < 128; ks += 32) {
            bf16x8 a = ld_frag(&lds_a[nn*136 + ks + qd*8]);
            #pragma unroll
            for (int tt = 0; tt < 6; tt++) {
                bf16x8 bb = ld_frag(&lcatT[((size_t)((wv*6 + tt)*16 + nn))*128 + ks + qd*8]);
                acc[tt] = __builtin_amdgcn_mfma_f32_16x16x32_bf16(a, bb, acc[tt], 0, 0, 0);
            }
        }
        float* Ps_a = msg;          // [128]
        float* Ps_b = msg + 128;    // [128]
        float* Pv   = msg + 256;    // [3][128]
        #pragma unroll
        for (int tt = 0; tt < 6; tt++) {
            int n = (wv*6 + tt)*16 + nn;
            #pragma unroll
            for (int i = 0; i < 4; i++) {
                int r = qd*4 + i;
                float val = acc[tt][i];
                if (r == 0 && n < 128) Ps_a[n] = val;
                else if (r == 1 && n >= 256) Ps_b[n - 256] = val;
                else if (r >= 2 && r < 5 && n >= 128 && n < 256)
                    Pv[(r-2)*128 + (n-128)] = val;
            }
        }
    }
    __syncthreads();

    for (int idx = t; idx < 512; idx += 256) {
        if (idx < 128) {
            int c = idx;
            float s1 = msg[c] + msg[128 + c];
            featsb[(size_t)node*704 + c] = f2bf(s1);
            h1g[(size_t)node*128 + c] = silu_f(s1);
        } else {
            int vi = idx - 128;
            int m = vi >> 7, c = vi & 127;
            float v = msg[256 + m*128 + c];
            v1g[(size_t)node*384 + m*128 + c] = v;
            featsb[(size_t)node*704 + 128 + m*128 + c] = f2bf(v);
        }
    }
    if (t == 0) featsb[(size_t)node*704 + 640] = f2bf(timeg[b]);
    if (t < 63) featsb[(size_t)node*704 + 641 + t] = 0;   // zero K-pad
}

// ---------------------------------------------------------------------------
// Kernel 3 (pass 2): L0 MFMA, L1/L2 MFMA, we2 via MFMA, combine, s2.
// ---------------------------------------------------------------------------
__global__ __launch_bounds__(256) void pass2_kernel(
    const float* __restrict__ rad, const float* __restrict__ Y1g,
    const float* __restrict__ maskg,
    const short* __restrict__ w0T, const float* __restrict__ b0,
    const short* __restrict__ w1T, const float* __restrict__ b1,
    const short* __restrict__ w2T, const float* __restrict__ b2,
    const short* __restrict__ w3T, const float* __restrict__ b3,
    const float* __restrict__ mix2,
    const float* __restrict__ h1g, const float* __restrict__ v1g,
    short* __restrict__ featsb)
{
    __shared__ __align__(16) short rad_bf[2560];  // [64][40]
    __shared__ __align__(16) short actA[64*72];
    __shared__ __align__(16) short actB[64*72];
    __shared__ float Y1s[64*4];
    __shared__ float mask_s[64];
    __shared__ float msgab[128];
    int t = threadIdx.x;
    int wv = t >> 6, lane = t & 63, qd = lane >> 4, nn = lane & 15;
    int node = blockIdx.x;
    int b = node >> 6;
    size_t pbase = (size_t)node * 64;

    for (int idx = t; idx < 2048; idx += 256) {
        int j = idx >> 5, k = idx & 31;
        rad_bf[j*40 + k] = (k < 8) ? f2bf(rad[pbase*8 + j*8 + k]) : (short)0;
    }
    if (t < 64) {
        mask_s[t] = maskg[pbase + t];
        #pragma unroll
        for (int m = 0; m < 3; m++) Y1s[t*4 + m] = Y1g[(pbase+t)*3 + m];
    }
    if (t < 128) msgab[t] = 0.f;
    __syncthreads();

    mfma_layer0(rad_bf, w0T, b0, actA, wv, qd, nn);
    __syncthreads();
    mfma_layer(actA, w1T, b1, actB, wv, qd, nn);
    __syncthreads();
    mfma_layer(actB, w2T, b2, actA, wv, qd, nn);   // hc -> actA
    __syncthreads();

    // we2 = hc @ w3 : [64 rows][256 cols]; wave owns rows [16wv,16wv+16),
    // 4 groups of 4 n-tiles to bound VGPR.
    for (int g = 0; g < 4; g++) {
        floatx4 acc[4];
        #pragma unroll
        for (int tt = 0; tt < 4; tt++) acc[tt] = (floatx4){0.f, 0.f, 0.f, 0.f};
        #pragma unroll
        for (int ks = 0; ks < 64; ks += 32) {
            bf16x8 a = ld_frag(&actA[(wv*16 + nn)*72 + ks + qd*8]);
            #pragma unroll
            for (int tt = 0; tt < 4; tt++) {
                int col0 = g*64 + tt*16;
                bf16x8 bb = ld_frag(&w3T[(col0 + nn)*64 + ks + qd*8]);
                acc[tt] = __builtin_amdgcn_mfma_f32_16x16x32_bf16(a, bb, acc[tt], 0, 0, 0);
            }
        }
        #pragma unroll
        for (int tt = 0; tt < 4; tt++) {
            int col = g*64 + tt*16 + nn;
            float bias = b3[col];
            int k = col & 127;
            float p = 0.f;
            if (col < 128) {
                #pragma unroll
                for (int i = 0; i < 4; i++) {
                    int j = wv*16 + qd*4 + i;
                    float we = (acc[tt][i] + bias) * mask_s[j];
                    p += we * h1g[((size_t)b*64 + j)*128 + k];
                }
            } else {
                #pragma unroll
                for (int i = 0; i < 4; i++) {
                    int j = wv*16 + qd*4 + i;
                    float we = (acc[tt][i] + bias) * mask_s[j];
                    const float* vb = &v1g[((size_t)b*64 + j)*384 + k];
                    float inv = Y1s[j*4+0]*vb[0] + Y1s[j*4+1]*vb[128] + Y1s[j*4+2]*vb[256];
                    p += we * inv;
                }
            }
            p += __shfl_xor(p, 16);
            p += __shfl_xor(p, 32);
            if (qd == 0) atomicAdd(&msgab[k], p);
        }
    }
    __syncthreads();

    if (t < 128) {
        int c = t;
        float acc = 0.f;
        for (int k = 0; k < 128; k++) acc += msgab[k] * mix2[k*128 + c];
        featsb[(size_t)node*704 + 512 + c] = f2bf(acc * 0.0625f);   // s2
    }
}

// ---------------------------------------------------------------------------
// Kernel 4: bf16 MFMA GEMM, C[M][ldo] = relu(A[M][lda] @ WT^T + bias), bf16 out.
// ---------------------------------------------------------------------------
__global__ __launch_bounds__(256) void gemm_mfma_kernel(
    const short* __restrict__ A, int lda,
    const short* __restrict__ BT, int ldb, int K,
    const float* __restrict__ bias, short* __restrict__ Cout, int ldo)
{
    __shared__ short As[64*72];
    __shared__ short Bs[64*72];
    int t = threadIdx.x;
    int wv = t >> 6, lane = t & 63, qd = lane >> 4, nn = lane & 15;
    int m0 = blockIdx.x * 64, n0 = blockIdx.y * 64;
    floatx4 acc[4];
    #pragma unroll
    for (int tt = 0; tt < 4; tt++) acc[tt] = (floatx4){0.f, 0.f, 0.f, 0.f};

    for (int kc = 0; kc < K; kc += 64) {
        for (int s = t; s < 512; s += 256) {
            int j = s >> 3, kk = (s & 7) * 8;
            *(uint4*)&As[j*72 + kk] = *(const uint4*)&A[(size_t)(m0 + j)*lda + kc + kk];
            *(uint4*)&Bs[j*72 + kk] = *(const uint4*)&BT[(size_t)(n0 + j)*ldb + kc + kk];
        }
        __syncthreads();
        #pragma unroll
        for (int ks = 0; ks < 64; ks += 32) {
            bf16x8 a = ld_frag(&As[(wv*16 + nn)*72 + ks + qd*8]);
            #pragma unroll
            for (int tt = 0; tt < 4; tt++) {
                bf16x8 bb = ld_frag(&Bs[(tt*16 + nn)*72 + ks + qd*8]);
                acc[tt] = __builtin_amdgcn_mfma_f32_16x16x32_bf16(a, bb, acc[tt], 0, 0, 0);
            }
        }
        __syncthreads();
    }
    #pragma unroll
    for (int tt = 0; tt < 4; tt++) {
        int n = n0 + tt*16 + nn;
        float bv = bias[n];
        #pragma unroll
        for (int i = 0; i < 4; i++) {
            int m = m0 + wv*16 + qd*4 + i;
            Cout[(size_t)m*ldo + n] = f2bf(fmaxf(acc[tt][i] + bv, 0.f));
        }
    }
}

// ---------------------------------------------------------------------------
// Kernel 5: out[node,3] = H(bf16)[node,512] @ w2[512,3] + b2. One wave/node.
// ---------------------------------------------------------------------------
__global__ __launch_bounds__(64) void final3_kernel(
    const short* __restrict__ H, const float* __restrict__ w2,
    const float* __restrict__ b2, float* __restrict__ out)
{
    int node = blockIdx.x, lane = threadIdx.x;
    float a0 = 0.f, a1 = 0.f, a2 = 0.f;
    #pragma unroll
    for (int r = 0; r < 8; r++) {
        int k = r*64 + lane;
        float h = bf2f(H[(size_t)node*512 + k]);
        a0 += h * w2[k*3 + 0];
        a1 += h * w2[k*3 + 1];
        a2 += h * w2[k*3 + 2];
    }
    #pragma unroll
    for (int off = 32; off > 0; off >>= 1) {
        a0 += __shfl_down(a0, off);
        a1 += __shfl_down(a1, off);
        a2 += __shfl_down(a2, off);
    }
    if (lane == 0) {
        out[(size_t)node*3 + 0] = a0 + b2[0];
        out[(size_t)node*3 + 1] = a1 + b2[1];
        out[(size_t)node*3 + 2] = a2 + b2[2];
    }
}

extern "C" void kernel_launch(void* const* d_in, const int* in_sizes, int n_in,
                              void* d_out, int out_size, void* d_ws, size_t ws_size,
                              hipStream_t stream) {
    const float* pos   = (const float*)d_in[0];
    const float* timeg = (const float*)d_in[1];
    const float* cell  = (const float*)d_in[2];
    const float* wemb  = (const float*)d_in[3];
    const float* r1w0  = (const float*)d_in[4];
    const float* r1b0  = (const float*)d_in[5];
    const float* r1w1  = (const float*)d_in[6];
    const float* r1b1  = (const float*)d_in[7];
    const float* r1w2  = (const float*)d_in[8];
    const float* r1b2  = (const float*)d_in[9];
    const float* r1w3  = (const float*)d_in[10];
    const float* r1b3  = (const float*)d_in[11];
    const float* l0    = (const float*)d_in[12];
    const float* l1    = (const float*)d_in[13];
    const float* l2    = (const float*)d_in[14];
    const float* r2w0  = (const float*)d_in[15];
    const float* r2b0  = (const float*)d_in[16];
    const float* r2w1  = (const float*)d_in[17];
    const float* r2b1  = (const float*)d_in[18];
    const float* r2w2  = (const float*)d_in[19];
    const float* r2b2  = (const float*)d_in[20];
    const float* r2w3  = (const float*)d_in[21];
    const float* r2b3  = (const float*)d_in[22];
    const float* mix2  = (const float*)d_in[23];
    const float* mw0   = (const float*)d_in[24];
    const float* mb0   = (const float*)d_in[25];
    const float* mw1   = (const float*)d_in[26];
    const float* mb1   = (const float*)d_in[27];
    const float* mw2   = (const float*)d_in[28];
    const float* mb2   = (const float*)d_in[29];

    float* ws    = (float*)d_ws;
    float* rad   = ws;                                   // 1,048,576 f
    float* Y1    = rad   + (size_t)NPAIR*8;              //   393,216 f
    float* Y2    = Y1    + (size_t)NPAIR*3;              //   655,360 f
    float* maskf = Y2    + (size_t)NPAIR*5;              //   131,072 f
    float* h1    = maskf + (size_t)NPAIR;                //   262,144 f
    float* v1    = h1    + (size_t)B_*N_*K_;             //   786,432 f
    short* featsb = (short*)(v1 + (size_t)B_*N_*3*K_);   // 1,441,792 sh (2048x704)
    short* prep  = featsb + (size_t)2048*704;            //   733,184 sh
    short* w1T_1 = prep;
    short* w2T_1 = prep + 4096;
    short* w1T_2 = prep + 8192;
    short* w2T_2 = prep + 12288;
    short* w3T_2 = prep + 16384;
    short* wT0   = prep + 32768;     // [512][704]
    short* wT1   = prep + 393216;    // [512][512]
    short* w0T_1 = prep + 655360;    // [64][32]
    short* w0T_2 = prep + 657408;    // [64][32]
    short* w3T_1 = prep + 659456;    // [384][64]
    short* lcatT = prep + 684032;    // [384][128]
    // final-MLP activations alias dead geometry buffers (sequenced after pass2):
    short* h0bb = (short*)rad;       // 2048x512 bf16 = 2 MB <= rad (4 MB)
    short* h1bb = (short*)Y2;        // 2048x512 bf16 = 2 MB <= Y2 (2.6 MB)

    prep_kernel<<<(PREP_TOTAL + 255)/256, 256, 0, stream>>>(
        r1w1, r1w2, r2w1, r2w2, r2w3, mw0, mw1,
        r1w0, r2w0, r1w3, l0, l1, l2, prep);
    geom_kernel<<<NPAIR/256, 256, 0, stream>>>(pos, cell, rad, Y1, Y2, maskf);
    pass1_kernel<<<B_*N_, 256, 0, stream>>>(rad, Y1, Y2, maskf, wemb,
        w0T_1, r1b0, w1T_1, r1b1, w2T_1, r1b2, w3T_1, r1b3, lcatT, timeg,
        h1, v1, featsb);
    pass2_kernel<<<B_*N_, 256, 0, stream>>>(rad, Y1, maskf,
        w0T_2, r2b0, w1T_2, r2b1, w2T_2, r2b2, w3T_2, r2b3, mix2, h1, v1, featsb);
    dim3 g0(32, 8);
    gemm_mfma_kernel<<<g0, 256, 0, stream>>>(featsb, 704, wT0, 704, 704, mb0, h0bb, 512);
    gemm_mfma_kernel<<<g0, 256, 0, stream>>>(h0bb, 512, wT1, 512, 512, mb1, h1bb, 512);
    final3_kernel<<<B_*N_, 64, 0, stream>>>(h1bb, mw2, mb2, (float*)d_out);
}